// Round 11
// baseline (1018.518 us; speedup 1.0000x reference)
//
#include <hip/hip_runtime.h>
#include <stdint.h>

#define NN   20000
#define NNP  20096   // padded rows (157*128)
#define NE   320000
#define GEPS 1e-10f
#define NBLK 768     // 3 blocks/CU x 256 CUs; residency guaranteed by __launch_bounds__(256,3)
#define EPW  16

typedef __attribute__((ext_vector_type(8))) __bf16 bf16x8;
typedef __attribute__((ext_vector_type(4))) float f32x4;

// Fragment-order layout: chunk (kt,fkh) of row r lives at ((kt*4+fkh)*ROWS + r)*8.
// A wave's MFMA fragment load (fr=lane&15, fkh=lane>>4) is then 4x contiguous 256B.

// ======================= init: zero barrier vars + masks =======================
__global__ __launch_bounds__(256) void init_k(int* __restrict__ bar, ulonglong2* __restrict__ mask2)
{
    const int t = blockIdx.x * 256 + threadIdx.x;
    if (t < 8) bar[t] = 0;
    if (t < NN) mask2[t] = make_ulonglong2(0ull, 0ull);
}

// ======================= device-scope grid barrier (relative generation) =======================
__device__ __forceinline__ void gridbar(int id, int* __restrict__ cnt, int* __restrict__ gen)
{
    __syncthreads();
    if (threadIdx.x == 0) {
        __threadfence();   // publish this block's writes device-wide
        const int g0 = __hip_atomic_load(&gen[id], __ATOMIC_ACQUIRE, __HIP_MEMORY_SCOPE_AGENT);
        const int arr = __hip_atomic_fetch_add(&cnt[id], 1, __ATOMIC_ACQ_REL, __HIP_MEMORY_SCOPE_AGENT);
        if (arr == NBLK - 1) {
            __hip_atomic_store(&cnt[id], 0, __ATOMIC_RELAXED, __HIP_MEMORY_SCOPE_AGENT);
            __hip_atomic_fetch_add(&gen[id], 1, __ATOMIC_ACQ_REL, __HIP_MEMORY_SCOPE_AGENT);
        } else {
            while (__hip_atomic_load(&gen[id], __ATOMIC_ACQUIRE, __HIP_MEMORY_SCOPE_AGENT) == g0)
                __builtin_amdgcn_s_sleep(2);
        }
        __threadfence();
    }
    __syncthreads();
}

// ======================= mega kernel: prep | logits->rtab | edges | gates =======================
__global__ __launch_bounds__(256, 3) void mega_k(
    const float* __restrict__ feat,  const float* __restrict__ hst,
    const int*   __restrict__ src,   const int* __restrict__ dst,
    const float* __restrict__ u,
    const float* __restrict__ W_enc, const float* __restrict__ b_enc,
    const float* __restrict__ W_dec, const float* __restrict__ b_dec,
    const float* __restrict__ W_ih,  const float* __restrict__ W_hh,
    const float* __restrict__ b_ih,  const float* __restrict__ b_hh,
    __bf16* __restrict__ B1h, __bf16* __restrict__ B1l,
    __bf16* __restrict__ B2h, __bf16* __restrict__ B2l,
    float* __restrict__ bias1, float* __restrict__ bias2,
    float* __restrict__ W_comb, unsigned long long* __restrict__ masks,
    __bf16* __restrict__ Aph, __bf16* __restrict__ Apl,
    float* __restrict__ rtab, int* __restrict__ bar,
    float* __restrict__ out)
{
    __shared__ float bd[128];
    const int t = threadIdx.x;
    const int lane = t & 63, wid = t >> 6;
    int* cnt = bar;
    int* gen = bar + 4;

    // ---------------- P0: pack weights + split A (fragment order) + fold biases ----------------
    for (int task = blockIdx.x; task < 3347; task += NBLK) {
        if (task < 128) {
            // B1: permuted W_enc row task
            const int srow = (task >> 6) * 64 + (task & 31) * 2 + ((task >> 5) & 1);
            const float v = W_enc[srow * 256 + t];
            const __bf16 hi = (__bf16)v;
            const int kt = t >> 5, fkh = (t >> 3) & 3, e = t & 7;
            const size_t idx = ((size_t)(kt * 4 + fkh) * 128 + task) * 8 + e;
            B1h[idx] = hi;
            B1l[idx] = (__bf16)(v - (float)hi);
        } else if (task < 640) {
            const int r2 = task - 128;
            const int nb = r2 >> 7, rem = r2 & 127, g = rem >> 5, jj = rem & 31;
            const int j = nb * 32 + jj;
            const int k = t;
            float v;
            if (g == 0)      v = (k < 128) ? W_ih[j * 256 + k]         : W_hh[j * 128 + (k - 128)];
            else if (g == 1) v = (k < 128) ? W_ih[(128 + j) * 256 + k] : W_hh[(128 + j) * 128 + (k - 128)];
            else if (g == 2) v = (k < 128) ? W_ih[(256 + j) * 256 + k] : 0.f;
            else             v = (k < 128) ? 0.f                       : W_hh[(256 + j) * 128 + (k - 128)];
            const __bf16 hi = (__bf16)v;
            const int kt = t >> 5, fkh = (t >> 3) & 3, e = t & 7;
            const size_t idx = ((size_t)(kt * 4 + fkh) * 512 + r2) * 8 + e;
            B2h[idx] = hi;
            B2l[idx] = (__bf16)(v - (float)hi);
        } else if (task < 832) {
            const int idx = (task - 640) * 256 + t;
            const int o = idx >> 7, k = idx & 127;
            float s = 0.f;
            for (int l = 0; l < 128; ++l)
                s += W_ih[o * 256 + 128 + l] * W_dec[l * 128 + k];
            W_comb[idx] = s;
        } else if (task < 835) {
            if (t < 128) {
                float s = b_dec[t];
                for (int k = 0; k < 128; ++k) s += W_dec[t * 128 + k];
                bd[t] = s;
            }
            __syncthreads();
            const int g = (task - 832) * 256 + t;   // 0..767
            if (g < 128) {
                bias1[g] = b_enc[(g >> 6) * 64 + (g & 31) * 2 + ((g >> 5) & 1)];
            } else if (g < 640) {
                const int c2 = g - 128;
                const int nb = c2 >> 7, rem = c2 & 127, gg = rem >> 5, jj = rem & 31;
                const int j = nb * 32 + jj;
                float v;
                if (gg == 3) v = b_hh[256 + j];
                else {
                    const int o = gg * 128 + j;
                    float s = (gg == 2) ? b_ih[o] : (b_ih[o] + b_hh[o]);
                    for (int l = 0; l < 128; ++l) s += W_ih[o * 256 + 128 + l] * bd[l];
                    v = s;
                }
                bias2[c2] = v;
            }
            __syncthreads();
        } else {
            // A split into fragment order: 8 rows/task, 32 chunks of 8 elems
            const int blk = task - 835;           // 0..2511
            const int row = blk * 8 + (t & 7);
            const int k0  = (t >> 3) * 8;         // 0..248
            float x[8];
            if (row < NN) {
                const float* sp = (k0 < 128) ? (feat + (size_t)row * 128 + k0)
                                             : (hst  + (size_t)row * 128 + (k0 - 128));
                const float4 v0 = *(const float4*)sp;
                const float4 v1 = *(const float4*)(sp + 4);
                x[0] = v0.x; x[1] = v0.y; x[2] = v0.z; x[3] = v0.w;
                x[4] = v1.x; x[5] = v1.y; x[6] = v1.z; x[7] = v1.w;
            } else {
#pragma unroll
                for (int i = 0; i < 8; ++i) x[i] = 0.f;
            }
            bf16x8 hi, lo;
#pragma unroll
            for (int i = 0; i < 8; ++i) {
                const __bf16 hv = (__bf16)x[i];
                hi[i] = hv;
                lo[i] = (__bf16)(x[i] - (float)hv);
            }
            const int kt = k0 >> 5, fkh = (k0 >> 3) & 3;
            const size_t idx = ((size_t)(kt * 4 + fkh) * NNP + row) * 8;
            *(bf16x8*)(Aph + idx) = hi;
            *(bf16x8*)(Apl + idx) = lo;
        }
    }

    gridbar(0, cnt, gen);

    // ---------------- P1: logits GEMM -> rtab ----------------
    for (int task = blockIdx.x; task < 313; task += NBLK) {
        const int m0 = task * 64;
        const int wm = (wid >> 1) * 32, wn = (wid & 1) * 64;
        const int fr = lane & 15, fkh = lane >> 4;

        f32x4 acc[2][4];
#pragma unroll
        for (int i = 0; i < 2; ++i)
#pragma unroll
            for (int j = 0; j < 4; ++j) acc[i][j] = (f32x4){0.f, 0.f, 0.f, 0.f};

        for (int kt = 0; kt < 8; ++kt) {
            const size_t ab = (size_t)(kt * 4 + fkh) * NNP;
            const size_t bb = (size_t)(kt * 4 + fkh) * 128;
            bf16x8 ah[2], al[2];
#pragma unroll
            for (int mf = 0; mf < 2; ++mf) {
                const size_t ro = (ab + m0 + wm + mf * 16 + fr) * 8;
                ah[mf] = *(const bf16x8*)(Aph + ro);
                al[mf] = *(const bf16x8*)(Apl + ro);
            }
#pragma unroll
            for (int nf = 0; nf < 4; ++nf) {
                const size_t ro = (bb + wn + nf * 16 + fr) * 8;
                const bf16x8 bh = *(const bf16x8*)(B1h + ro);
                const bf16x8 bl = *(const bf16x8*)(B1l + ro);
#pragma unroll
                for (int mf = 0; mf < 2; ++mf) {
                    acc[mf][nf] = __builtin_amdgcn_mfma_f32_16x16x32_bf16(ah[mf], bh, acc[mf][nf], 0, 0, 0);
                    acc[mf][nf] = __builtin_amdgcn_mfma_f32_16x16x32_bf16(al[mf], bh, acc[mf][nf], 0, 0, 0);
                    acc[mf][nf] = __builtin_amdgcn_mfma_f32_16x16x32_bf16(ah[mf], bl, acc[mf][nf], 0, 0, 0);
                }
            }
        }
#pragma unroll
        for (int nf = 0; nf < 2; ++nf) {
            const int c0 = wn + nf * 16 + fr;
            const float b0 = bias1[c0], b1 = bias1[c0 + 32];
            const int j = (wid & 1) * 32 + nf * 16 + fr;
#pragma unroll
            for (int mf = 0; mf < 2; ++mf)
#pragma unroll
                for (int rr = 0; rr < 4; ++rr) {
                    const int gr = m0 + wm + mf * 16 + (lane >> 4) * 4 + rr;
                    if (gr < NN)
                        rtab[(size_t)gr * 64 + j] =
                            expf((acc[mf][nf + 2][rr] + b1) - (acc[mf][nf][rr] + b0));
                }
        }
    }

    gridbar(1, cnt, gen);

    // ---------------- P2: per-edge gumbel argmax -> OR masks ----------------
    for (int task = blockIdx.x; task < NE / (4 * EPW); task += NBLK) {
        const int e0 = __builtin_amdgcn_readfirstlane(task * 4 + wid) * EPW;
        float2 uu[EPW];
        float  rr[EPW];
        int    dd[EPW];
#pragma unroll
        for (int i = 0; i < EPW; ++i) {
            const int e = e0 + i;
            uu[i] = *(const float2*)(u + (size_t)e * 128 + lane * 2);
            rr[i] = rtab[(size_t)src[e] * 64 + lane];
            dd[i] = dst[e];
        }
#pragma unroll
        for (int i = 0; i < EPW; ++i) {
            const float a0 = GEPS - logf(uu[i].x + GEPS);
            const float a1 = GEPS - logf(uu[i].y + GEPS);
            const unsigned long long mone = __ballot(rr[i] * a0 > a1);
            if (lane == 0) {
                atomicOr(&masks[(size_t)dd[i] * 2 + 1], mone);
                atomicOr(&masks[(size_t)dd[i] * 2 + 0], ~mone);
            }
        }
    }

    gridbar(2, cnt, gen);

    // ---------------- P3: gate GEMM + fused GRU epilogue -> out ----------------
    for (int task = blockIdx.x; task < 4 * (NNP / 128); task += NBLK) {
        const int nb = task & 3, m0 = (task >> 2) * 128;
        const int wm = wid * 32;
        const int fr = lane & 15, fkh = lane >> 4;

        f32x4 acc[2][8];
#pragma unroll
        for (int i = 0; i < 2; ++i)
#pragma unroll
            for (int j = 0; j < 8; ++j) acc[i][j] = (f32x4){0.f, 0.f, 0.f, 0.f};

        for (int kt = 0; kt < 8; ++kt) {
            const size_t ab = (size_t)(kt * 4 + fkh) * NNP;
            const size_t bb = (size_t)(kt * 4 + fkh) * 512;
            bf16x8 ah[2], al[2];
#pragma unroll
            for (int mf = 0; mf < 2; ++mf) {
                const size_t ro = (ab + m0 + wm + mf * 16 + fr) * 8;
                ah[mf] = *(const bf16x8*)(Aph + ro);
                al[mf] = *(const bf16x8*)(Apl + ro);
            }
#pragma unroll
            for (int nf = 0; nf < 8; ++nf) {
                const size_t ro = (bb + nb * 128 + nf * 16 + fr) * 8;
                const bf16x8 bh = *(const bf16x8*)(B2h + ro);
                const bf16x8 bl = *(const bf16x8*)(B2l + ro);
#pragma unroll
                for (int mf = 0; mf < 2; ++mf) {
                    acc[mf][nf] = __builtin_amdgcn_mfma_f32_16x16x32_bf16(ah[mf], bh, acc[mf][nf], 0, 0, 0);
                    acc[mf][nf] = __builtin_amdgcn_mfma_f32_16x16x32_bf16(al[mf], bh, acc[mf][nf], 0, 0, 0);
                    acc[mf][nf] = __builtin_amdgcn_mfma_f32_16x16x32_bf16(ah[mf], bl, acc[mf][nf], 0, 0, 0);
                }
            }
        }

        float bia[8];
#pragma unroll
        for (int nf = 0; nf < 8; ++nf) bia[nf] = bias2[nb * 128 + nf * 16 + fr];

#pragma unroll
        for (int mf = 0; mf < 2; ++mf)
#pragma unroll
            for (int rr = 0; rr < 4; ++rr) {
                const int gr = m0 + wm + mf * 16 + (lane >> 4) * 4 + rr;
                if (gr >= NN) continue;
                const unsigned long long ze = ~masks[(size_t)gr * 2 + 0];
                const unsigned long long zo = ~masks[(size_t)gr * 2 + 1];
#pragma unroll
                for (int jh = 0; jh < 2; ++jh) {
                    const int j = nb * 32 + jh * 16 + fr;
                    float rp = acc[mf][0 + jh][rr] + bia[0 + jh];
                    float zp = acc[mf][2 + jh][rr] + bia[2 + jh];
                    float ip = acc[mf][4 + jh][rr] + bia[4 + jh];
                    float hp = acc[mf][6 + jh][rr] + bia[6 + jh];
                    if (ze | zo) {
                        unsigned long long bz = ze;
#pragma unroll 1
                        while (bz) {
                            const int k = __builtin_ctzll(bz); bz &= bz - 1;
                            const int bit = 2 * k;
                            rp -= W_comb[(size_t)j * 128 + bit];
                            zp -= W_comb[(size_t)(128 + j) * 128 + bit];
                            ip -= W_comb[(size_t)(256 + j) * 128 + bit];
                        }
                        bz = zo;
#pragma unroll 1
                        while (bz) {
                            const int k = __builtin_ctzll(bz); bz &= bz - 1;
                            const int bit = 2 * k + 1;
                            rp -= W_comb[(size_t)j * 128 + bit];
                            zp -= W_comb[(size_t)(128 + j) * 128 + bit];
                            ip -= W_comb[(size_t)(256 + j) * 128 + bit];
                        }
                    }
                    const float hv = hst[(size_t)gr * 128 + j];
                    const float rg = 1.f / (1.f + expf(-rp));
                    const float zg = 1.f / (1.f + expf(-zp));
                    const float nv = tanhf(ip + rg * hp);
                    const float o = (1.f - zg) * nv + zg * hv;
                    out[(size_t)gr * 128 + j] = o;
                    out[(size_t)(NN + gr) * 128 + j] = o;
                }
            }
    }
}

extern "C" void kernel_launch(void* const* d_in, const int* in_sizes, int n_in,
                              void* d_out, int out_size, void* d_ws, size_t ws_size,
                              hipStream_t stream) {
    const float* feat  = (const float*)d_in[0];
    const float* h     = (const float*)d_in[1];
    const int*   src   = (const int*)d_in[2];
    const int*   dst   = (const int*)d_in[3];
    const float* u     = (const float*)d_in[4];
    const float* W_enc = (const float*)d_in[5];
    const float* b_enc = (const float*)d_in[6];
    const float* W_dec = (const float*)d_in[7];
    const float* b_dec = (const float*)d_in[8];
    const float* W_ih  = (const float*)d_in[9];
    const float* W_hh  = (const float*)d_in[10];
    const float* b_ih  = (const float*)d_in[11];
    const float* b_hh  = (const float*)d_in[12];
    float* out = (float*)d_out;
    (void)in_sizes; (void)n_in; (void)out_size; (void)ws_size;

    char* ws = (char*)d_ws;
    float*              rtab   = (float*)(ws + 0);                    // 5,120,000 B
    unsigned long long* masks  = (unsigned long long*)(ws + 5120000); //   320,000 B
    __bf16*             B1h    = (__bf16*)(ws + 5440000);             //    65,536 B
    __bf16*             B1l    = (__bf16*)(ws + 5505536);             //    65,536 B
    __bf16*             B2h    = (__bf16*)(ws + 5571072);             //   262,144 B
    __bf16*             B2l    = (__bf16*)(ws + 5833216);             //   262,144 B
    float*              bias1  = (float*)(ws + 6095360);              //       512 B
    float*              bias2  = (float*)(ws + 6095872);              //     2,048 B
    float*              W_comb = (float*)(ws + 6097920);              //   196,608 B
    __bf16*             Aph    = (__bf16*)(ws + 6294528);             // 10,289,152 B
    __bf16*             Apl    = (__bf16*)(ws + 16583680);            // 10,289,152 B
    int*                bar    = (int*)(ws + 26872832);               //        32 B

    // zero barrier state + masks (graph-replay safe: relative-generation barrier)
    init_k<<<(NN + 255) / 256, 256, 0, stream>>>(bar, (ulonglong2*)masks);

    // fused prep | logits->rtab | edges | gates (device-scope grid barriers between phases)
    mega_k<<<NBLK, 256, 0, stream>>>(
        feat, h, src, dst, u, W_enc, b_enc, W_dec, b_dec, W_ih, W_hh, b_ih, b_hh,
        B1h, B1l, B2h, B2l, bias1, bias2, W_comb, masks, Aph, Apl, rtab, bar, out);
}

// Round 13
// 627.095 us; speedup vs baseline: 1.6242x; 1.6242x over previous
//
#include <hip/hip_runtime.h>
#include <stdint.h>

#define NN   20000
#define NNP  20096   // padded rows (157*128)
#define NE   320000
#define GEPS 1e-10f
#define NBLK 768     // 3 blocks/CU x 256 CUs; residency guaranteed by __launch_bounds__(256,3)
#define EPW  16

typedef __attribute__((ext_vector_type(8))) __bf16 bf16x8;
typedef __attribute__((ext_vector_type(4))) float f32x4;

// Fragment-order layout: chunk (kt,fkh) of row r lives at ((kt*4+fkh)*ROWS + r)*8.
// A wave's MFMA fragment load (fr=lane&15, fkh=lane>>4) is then 4x contiguous 256B.

// ======================= init: zero barrier vars + masks =======================
__global__ __launch_bounds__(256) void init_k(int* __restrict__ bar, ulonglong2* __restrict__ mask2)
{
    const int t = blockIdx.x * 256 + threadIdx.x;
    if (t < 8) bar[t] = 0;
    if (t < NN) mask2[t] = make_ulonglong2(0ull, 0ull);
}

// ======================= device-scope grid barrier (relative generation) =======================
// CRITICAL (R11 lesson): poll with RELAXED loads. An ACQUIRE atomic load at agent scope
// emits buffer_inv on gfx950 -> spinning blocks invalidate their XCD's L2 every iteration,
// thrashing co-resident workers (measured: +150MB FETCH, 10x slowdown). One fence after
// wakeup does the invalidate exactly once.
__device__ __forceinline__ void gridbar(int id, int* __restrict__ cnt, int* __restrict__ gen)
{
    __syncthreads();
    if (threadIdx.x == 0) {
        __threadfence();   // release: write back this block's stores (wbL2)
        const int g0 = __hip_atomic_load(&gen[id], __ATOMIC_RELAXED, __HIP_MEMORY_SCOPE_AGENT);
        const int arr = __hip_atomic_fetch_add(&cnt[id], 1, __ATOMIC_RELAXED, __HIP_MEMORY_SCOPE_AGENT);
        if (arr == NBLK - 1) {
            __hip_atomic_store(&cnt[id], 0, __ATOMIC_RELAXED, __HIP_MEMORY_SCOPE_AGENT);
            __hip_atomic_fetch_add(&gen[id], 1, __ATOMIC_RELAXED, __HIP_MEMORY_SCOPE_AGENT);
        } else {
            while (__hip_atomic_load(&gen[id], __ATOMIC_RELAXED, __HIP_MEMORY_SCOPE_AGENT) == g0)
                __builtin_amdgcn_s_sleep(8);
        }
        __threadfence();   // acquire: invalidate caches ONCE after wakeup
    }
    __syncthreads();
}

// ======================= mega kernel: prep | logits->rtab | edges | gates =======================
__global__ __launch_bounds__(256, 3) void mega_k(
    const float* __restrict__ feat,  const float* __restrict__ hst,
    const int*   __restrict__ src,   const int* __restrict__ dst,
    const float* __restrict__ u,
    const float* __restrict__ W_enc, const float* __restrict__ b_enc,
    const float* __restrict__ W_dec, const float* __restrict__ b_dec,
    const float* __restrict__ W_ih,  const float* __restrict__ W_hh,
    const float* __restrict__ b_ih,  const float* __restrict__ b_hh,
    __bf16* __restrict__ B1h, __bf16* __restrict__ B1l,
    __bf16* __restrict__ B2h, __bf16* __restrict__ B2l,
    float* __restrict__ bias1, float* __restrict__ bias2,
    float* __restrict__ W_comb, unsigned long long* __restrict__ masks,
    __bf16* __restrict__ Aph, __bf16* __restrict__ Apl,
    float* __restrict__ rtab, int* __restrict__ bar,
    float* __restrict__ out)
{
    __shared__ float bd[128];
    const int t = threadIdx.x;
    const int lane = t & 63, wid = t >> 6;
    int* cnt = bar;
    int* gen = bar + 4;

    // ---------------- P0: pack weights + split A (fragment order) + fold biases ----------------
    for (int task = blockIdx.x; task < 3347; task += NBLK) {
        if (task < 128) {
            // B1: permuted W_enc row task
            const int srow = (task >> 6) * 64 + (task & 31) * 2 + ((task >> 5) & 1);
            const float v = W_enc[srow * 256 + t];
            const __bf16 hi = (__bf16)v;
            const int kt = t >> 5, fkh = (t >> 3) & 3, e = t & 7;
            const size_t idx = ((size_t)(kt * 4 + fkh) * 128 + task) * 8 + e;
            B1h[idx] = hi;
            B1l[idx] = (__bf16)(v - (float)hi);
        } else if (task < 640) {
            const int r2 = task - 128;
            const int nb = r2 >> 7, rem = r2 & 127, g = rem >> 5, jj = rem & 31;
            const int j = nb * 32 + jj;
            const int k = t;
            float v;
            if (g == 0)      v = (k < 128) ? W_ih[j * 256 + k]         : W_hh[j * 128 + (k - 128)];
            else if (g == 1) v = (k < 128) ? W_ih[(128 + j) * 256 + k] : W_hh[(128 + j) * 128 + (k - 128)];
            else if (g == 2) v = (k < 128) ? W_ih[(256 + j) * 256 + k] : 0.f;
            else             v = (k < 128) ? 0.f                       : W_hh[(256 + j) * 128 + (k - 128)];
            const __bf16 hi = (__bf16)v;
            const int kt = t >> 5, fkh = (t >> 3) & 3, e = t & 7;
            const size_t idx = ((size_t)(kt * 4 + fkh) * 512 + r2) * 8 + e;
            B2h[idx] = hi;
            B2l[idx] = (__bf16)(v - (float)hi);
        } else if (task < 832) {
            const int idx = (task - 640) * 256 + t;
            const int o = idx >> 7, k = idx & 127;
            float s = 0.f;
            for (int l = 0; l < 128; ++l)
                s += W_ih[o * 256 + 128 + l] * W_dec[l * 128 + k];
            W_comb[idx] = s;
        } else if (task < 835) {
            if (t < 128) {
                float s = b_dec[t];
                for (int k = 0; k < 128; ++k) s += W_dec[t * 128 + k];
                bd[t] = s;
            }
            __syncthreads();
            const int g = (task - 832) * 256 + t;   // 0..767
            if (g < 128) {
                bias1[g] = b_enc[(g >> 6) * 64 + (g & 31) * 2 + ((g >> 5) & 1)];
            } else if (g < 640) {
                const int c2 = g - 128;
                const int nb = c2 >> 7, rem = c2 & 127, gg = rem >> 5, jj = rem & 31;
                const int j = nb * 32 + jj;
                float v;
                if (gg == 3) v = b_hh[256 + j];
                else {
                    const int o = gg * 128 + j;
                    float s = (gg == 2) ? b_ih[o] : (b_ih[o] + b_hh[o]);
                    for (int l = 0; l < 128; ++l) s += W_ih[o * 256 + 128 + l] * bd[l];
                    v = s;
                }
                bias2[c2] = v;
            }
            __syncthreads();
        } else {
            // A split into fragment order: 8 rows/task, 32 chunks of 8 elems
            const int blk = task - 835;           // 0..2511
            const int row = blk * 8 + (t & 7);
            const int k0  = (t >> 3) * 8;         // 0..248
            float x[8];
            if (row < NN) {
                const float* sp = (k0 < 128) ? (feat + (size_t)row * 128 + k0)
                                             : (hst  + (size_t)row * 128 + (k0 - 128));
                const float4 v0 = *(const float4*)sp;
                const float4 v1 = *(const float4*)(sp + 4);
                x[0] = v0.x; x[1] = v0.y; x[2] = v0.z; x[3] = v0.w;
                x[4] = v1.x; x[5] = v1.y; x[6] = v1.z; x[7] = v1.w;
            } else {
#pragma unroll
                for (int i = 0; i < 8; ++i) x[i] = 0.f;
            }
            bf16x8 hi, lo;
#pragma unroll
            for (int i = 0; i < 8; ++i) {
                const __bf16 hv = (__bf16)x[i];
                hi[i] = hv;
                lo[i] = (__bf16)(x[i] - (float)hv);
            }
            const int kt = k0 >> 5, fkh = (k0 >> 3) & 3;
            const size_t idx = ((size_t)(kt * 4 + fkh) * NNP + row) * 8;
            *(bf16x8*)(Aph + idx) = hi;
            *(bf16x8*)(Apl + idx) = lo;
        }
    }

    gridbar(0, cnt, gen);

    // ---------------- P1: logits GEMM -> rtab ----------------
    for (int task = blockIdx.x; task < 313; task += NBLK) {
        const int m0 = task * 64;
        const int wm = (wid >> 1) * 32, wn = (wid & 1) * 64;
        const int fr = lane & 15, fkh = lane >> 4;

        f32x4 acc[2][4];
#pragma unroll
        for (int i = 0; i < 2; ++i)
#pragma unroll
            for (int j = 0; j < 4; ++j) acc[i][j] = (f32x4){0.f, 0.f, 0.f, 0.f};

        for (int kt = 0; kt < 8; ++kt) {
            const size_t ab = (size_t)(kt * 4 + fkh) * NNP;
            const size_t bb = (size_t)(kt * 4 + fkh) * 128;
            bf16x8 ah[2], al[2];
#pragma unroll
            for (int mf = 0; mf < 2; ++mf) {
                const size_t ro = (ab + m0 + wm + mf * 16 + fr) * 8;
                ah[mf] = *(const bf16x8*)(Aph + ro);
                al[mf] = *(const bf16x8*)(Apl + ro);
            }
#pragma unroll
            for (int nf = 0; nf < 4; ++nf) {
                const size_t ro = (bb + wn + nf * 16 + fr) * 8;
                const bf16x8 bh = *(const bf16x8*)(B1h + ro);
                const bf16x8 bl = *(const bf16x8*)(B1l + ro);
#pragma unroll
                for (int mf = 0; mf < 2; ++mf) {
                    acc[mf][nf] = __builtin_amdgcn_mfma_f32_16x16x32_bf16(ah[mf], bh, acc[mf][nf], 0, 0, 0);
                    acc[mf][nf] = __builtin_amdgcn_mfma_f32_16x16x32_bf16(al[mf], bh, acc[mf][nf], 0, 0, 0);
                    acc[mf][nf] = __builtin_amdgcn_mfma_f32_16x16x32_bf16(ah[mf], bl, acc[mf][nf], 0, 0, 0);
                }
            }
        }
#pragma unroll
        for (int nf = 0; nf < 2; ++nf) {
            const int c0 = wn + nf * 16 + fr;
            const float b0 = bias1[c0], b1 = bias1[c0 + 32];
            const int j = (wid & 1) * 32 + nf * 16 + fr;
#pragma unroll
            for (int mf = 0; mf < 2; ++mf)
#pragma unroll
                for (int rr = 0; rr < 4; ++rr) {
                    const int gr = m0 + wm + mf * 16 + (lane >> 4) * 4 + rr;
                    if (gr < NN)
                        rtab[(size_t)gr * 64 + j] =
                            expf((acc[mf][nf + 2][rr] + b1) - (acc[mf][nf][rr] + b0));
                }
        }
    }

    gridbar(1, cnt, gen);

    // ---------------- P2: per-edge gumbel argmax -> OR masks ----------------
    for (int task = blockIdx.x; task < NE / (4 * EPW); task += NBLK) {
        const int e0 = __builtin_amdgcn_readfirstlane(task * 4 + wid) * EPW;
        float2 uu[EPW];
        float  rr[EPW];
        int    dd[EPW];
#pragma unroll
        for (int i = 0; i < EPW; ++i) {
            const int e = e0 + i;
            uu[i] = *(const float2*)(u + (size_t)e * 128 + lane * 2);
            rr[i] = rtab[(size_t)src[e] * 64 + lane];
            dd[i] = dst[e];
        }
#pragma unroll
        for (int i = 0; i < EPW; ++i) {
            const float a0 = GEPS - logf(uu[i].x + GEPS);
            const float a1 = GEPS - logf(uu[i].y + GEPS);
            const unsigned long long mone = __ballot(rr[i] * a0 > a1);
            if (lane == 0) {
                atomicOr(&masks[(size_t)dd[i] * 2 + 1], mone);
                atomicOr(&masks[(size_t)dd[i] * 2 + 0], ~mone);
            }
        }
    }

    gridbar(2, cnt, gen);

    // ---------------- P3: gate GEMM + fused GRU epilogue -> out ----------------
    for (int task = blockIdx.x; task < 4 * (NNP / 128); task += NBLK) {
        const int nb = task & 3, m0 = (task >> 2) * 128;
        const int wm = wid * 32;
        const int fr = lane & 15, fkh = lane >> 4;

        f32x4 acc[2][8];
#pragma unroll
        for (int i = 0; i < 2; ++i)
#pragma unroll
            for (int j = 0; j < 8; ++j) acc[i][j] = (f32x4){0.f, 0.f, 0.f, 0.f};

        for (int kt = 0; kt < 8; ++kt) {
            const size_t ab = (size_t)(kt * 4 + fkh) * NNP;
            const size_t bb = (size_t)(kt * 4 + fkh) * 512;
            bf16x8 ah[2], al[2];
#pragma unroll
            for (int mf = 0; mf < 2; ++mf) {
                const size_t ro = (ab + m0 + wm + mf * 16 + fr) * 8;
                ah[mf] = *(const bf16x8*)(Aph + ro);
                al[mf] = *(const bf16x8*)(Apl + ro);
            }
#pragma unroll
            for (int nf = 0; nf < 8; ++nf) {
                const size_t ro = (bb + nb * 128 + nf * 16 + fr) * 8;
                const bf16x8 bh = *(const bf16x8*)(B2h + ro);
                const bf16x8 bl = *(const bf16x8*)(B2l + ro);
#pragma unroll
                for (int mf = 0; mf < 2; ++mf) {
                    acc[mf][nf] = __builtin_amdgcn_mfma_f32_16x16x32_bf16(ah[mf], bh, acc[mf][nf], 0, 0, 0);
                    acc[mf][nf] = __builtin_amdgcn_mfma_f32_16x16x32_bf16(al[mf], bh, acc[mf][nf], 0, 0, 0);
                    acc[mf][nf] = __builtin_amdgcn_mfma_f32_16x16x32_bf16(ah[mf], bl, acc[mf][nf], 0, 0, 0);
                }
            }
        }

        float bia[8];
#pragma unroll
        for (int nf = 0; nf < 8; ++nf) bia[nf] = bias2[nb * 128 + nf * 16 + fr];

#pragma unroll
        for (int mf = 0; mf < 2; ++mf)
#pragma unroll
            for (int rr = 0; rr < 4; ++rr) {
                const int gr = m0 + wm + mf * 16 + (lane >> 4) * 4 + rr;
                if (gr >= NN) continue;
                const unsigned long long ze = ~masks[(size_t)gr * 2 + 0];
                const unsigned long long zo = ~masks[(size_t)gr * 2 + 1];
#pragma unroll
                for (int jh = 0; jh < 2; ++jh) {
                    const int j = nb * 32 + jh * 16 + fr;
                    float rp = acc[mf][0 + jh][rr] + bia[0 + jh];
                    float zp = acc[mf][2 + jh][rr] + bia[2 + jh];
                    float ip = acc[mf][4 + jh][rr] + bia[4 + jh];
                    float hp = acc[mf][6 + jh][rr] + bia[6 + jh];
                    if (ze | zo) {
                        unsigned long long bz = ze;
#pragma unroll 1
                        while (bz) {
                            const int k = __builtin_ctzll(bz); bz &= bz - 1;
                            const int bit = 2 * k;
                            rp -= W_comb[(size_t)j * 128 + bit];
                            zp -= W_comb[(size_t)(128 + j) * 128 + bit];
                            ip -= W_comb[(size_t)(256 + j) * 128 + bit];
                        }
                        bz = zo;
#pragma unroll 1
                        while (bz) {
                            const int k = __builtin_ctzll(bz); bz &= bz - 1;
                            const int bit = 2 * k + 1;
                            rp -= W_comb[(size_t)j * 128 + bit];
                            zp -= W_comb[(size_t)(128 + j) * 128 + bit];
                            ip -= W_comb[(size_t)(256 + j) * 128 + bit];
                        }
                    }
                    const float hv = hst[(size_t)gr * 128 + j];
                    const float rg = 1.f / (1.f + expf(-rp));
                    const float zg = 1.f / (1.f + expf(-zp));
                    const float nv = tanhf(ip + rg * hp);
                    const float o = (1.f - zg) * nv + zg * hv;
                    out[(size_t)gr * 128 + j] = o;
                    out[(size_t)(NN + gr) * 128 + j] = o;
                }
            }
    }
}

extern "C" void kernel_launch(void* const* d_in, const int* in_sizes, int n_in,
                              void* d_out, int out_size, void* d_ws, size_t ws_size,
                              hipStream_t stream) {
    const float* feat  = (const float*)d_in[0];
    const float* h     = (const float*)d_in[1];
    const int*   src   = (const int*)d_in[2];
    const int*   dst   = (const int*)d_in[3];
    const float* u     = (const float*)d_in[4];
    const float* W_enc = (const float*)d_in[5];
    const float* b_enc = (const float*)d_in[6];
    const float* W_dec = (const float*)d_in[7];
    const float* b_dec = (const float*)d_in[8];
    const float* W_ih  = (const float*)d_in[9];
    const float* W_hh  = (const float*)d_in[10];
    const float* b_ih  = (const float*)d_in[11];
    const float* b_hh  = (const float*)d_in[12];
    float* out = (float*)d_out;
    (void)in_sizes; (void)n_in; (void)out_size; (void)ws_size;

    char* ws = (char*)d_ws;
    float*              rtab   = (float*)(ws + 0);                    // 5,120,000 B
    unsigned long long* masks  = (unsigned long long*)(ws + 5120000); //   320,000 B
    __bf16*             B1h    = (__bf16*)(ws + 5440000);             //    65,536 B
    __bf16*             B1l    = (__bf16*)(ws + 5505536);             //    65,536 B
    __bf16*             B2h    = (__bf16*)(ws + 5571072);             //   262,144 B
    __bf16*             B2l    = (__bf16*)(ws + 5833216);             //   262,144 B
    float*              bias1  = (float*)(ws + 6095360);              //       512 B
    float*              bias2  = (float*)(ws + 6095872);              //     2,048 B
    float*              W_comb = (float*)(ws + 6097920);              //   196,608 B
    __bf16*             Aph    = (__bf16*)(ws + 6294528);             // 10,289,152 B
    __bf16*             Apl    = (__bf16*)(ws + 16583680);            // 10,289,152 B
    int*                bar    = (int*)(ws + 26872832);               //        32 B

    // zero barrier state + masks (graph-replay safe: relative-generation barrier)
    init_k<<<(NN + 255) / 256, 256, 0, stream>>>(bar, (ulonglong2*)masks);

    // fused prep | logits->rtab | edges | gates (device-scope grid barriers between phases)
    mega_k<<<NBLK, 256, 0, stream>>>(
        feat, h, src, dst, u, W_enc, b_enc, W_dec, b_dec, W_ih, W_hh, b_ih, b_hh,
        B1h, B1l, B2h, B2l, bias1, bias2, W_comb, masks, Aph, Apl, rtab, bar, out);
}

// Round 14
// 106.312 us; speedup vs baseline: 9.5805x; 5.8986x over previous
//
#include <hip/hip_runtime.h>
#include <stdint.h>

#define NN   20000
#define NNP  20096   // padded rows (157*128)
#define NE   320000
#define GEPS 1e-10f

typedef __attribute__((ext_vector_type(8))) __bf16 bf16x8;
typedef __attribute__((ext_vector_type(4))) float f32x4;

// Fragment-order layout: chunk (kt,fkh) of row r lives at ((kt*4+fkh)*ROWS + r)*8.
// A wave's MFMA fragment load (fr=lane&15, fkh=lane>>4) is then 4x contiguous 256B.

// ======================= prep: pack weights + split A + zero masks =======================
__global__ __launch_bounds__(256) void prep_k(
    const float* __restrict__ feat,  const float* __restrict__ hst,
    const float* __restrict__ W_enc, const float* __restrict__ b_enc,
    const float* __restrict__ W_dec, const float* __restrict__ b_dec,
    const float* __restrict__ W_ih,  const float* __restrict__ W_hh,
    const float* __restrict__ b_ih,  const float* __restrict__ b_hh,
    __bf16* __restrict__ B1h, __bf16* __restrict__ B1l,
    __bf16* __restrict__ B2h, __bf16* __restrict__ B2l,
    float* __restrict__ bias1, float* __restrict__ bias2,
    float* __restrict__ W_comb, ulonglong2* __restrict__ mask2,
    __bf16* __restrict__ Aph, __bf16* __restrict__ Apl)
{
    const int b = blockIdx.x, t = threadIdx.x;
    if (b < 128) {
        const int src = (b >> 6) * 64 + (b & 31) * 2 + ((b >> 5) & 1);
        const float v = W_enc[src * 256 + t];
        const __bf16 hi = (__bf16)v;
        const int kt = t >> 5, fkh = (t >> 3) & 3, e = t & 7;
        const size_t idx = ((size_t)(kt * 4 + fkh) * 128 + b) * 8 + e;
        B1h[idx] = hi;
        B1l[idx] = (__bf16)(v - (float)hi);
    } else if (b < 640) {
        const int r2 = b - 128;
        const int nb = r2 >> 7, rem = r2 & 127, g = rem >> 5, jj = rem & 31;
        const int j = nb * 32 + jj;
        const int k = t;
        float v;
        if (g == 0)      v = (k < 128) ? W_ih[j * 256 + k]         : W_hh[j * 128 + (k - 128)];
        else if (g == 1) v = (k < 128) ? W_ih[(128 + j) * 256 + k] : W_hh[(128 + j) * 128 + (k - 128)];
        else if (g == 2) v = (k < 128) ? W_ih[(256 + j) * 256 + k] : 0.f;
        else             v = (k < 128) ? 0.f                       : W_hh[(256 + j) * 128 + (k - 128)];
        const __bf16 hi = (__bf16)v;
        const int kt = t >> 5, fkh = (t >> 3) & 3, e = t & 7;
        const size_t idx = ((size_t)(kt * 4 + fkh) * 512 + r2) * 8 + e;
        B2h[idx] = hi;
        B2l[idx] = (__bf16)(v - (float)hi);
    } else if (b < 832) {
        const int idx = (b - 640) * 256 + t;
        const int o = idx >> 7, k = idx & 127;
        float s = 0.f;
        for (int l = 0; l < 128; ++l)
            s += W_ih[o * 256 + 128 + l] * W_dec[l * 128 + k];
        W_comb[idx] = s;
    } else if (b < 835) {
        __shared__ float bd[128];
        if (t < 128) {
            float s = b_dec[t];
            for (int k = 0; k < 128; ++k) s += W_dec[t * 128 + k];
            bd[t] = s;
        }
        __syncthreads();
        const int g = (b - 832) * 256 + t;   // 0..767
        if (g < 128) {
            bias1[g] = b_enc[(g >> 6) * 64 + (g & 31) * 2 + ((g >> 5) & 1)];
        } else if (g < 640) {
            const int c2 = g - 128;
            const int nb = c2 >> 7, rem = c2 & 127, gg = rem >> 5, jj = rem & 31;
            const int j = nb * 32 + jj;
            float v;
            if (gg == 3) v = b_hh[256 + j];
            else {
                const int o = gg * 128 + j;
                float s = (gg == 2) ? b_ih[o] : (b_ih[o] + b_hh[o]);
                for (int l = 0; l < 128; ++l) s += W_ih[o * 256 + 128 + l] * bd[l];
                v = s;
            }
            bias2[c2] = v;
        }
    } else if (b < 914) {
        const int i = (b - 835) * 256 + t;
        if (i < NN) mask2[i] = make_ulonglong2(0ull, 0ull);
    } else {
        // A split into fragment order: 8 rows/block, 32 chunks of 8 elems
        const int blk = b - 914;              // 0..2511
        const int row = blk * 8 + (t & 7);
        const int k0  = (t >> 3) * 8;         // 0..248
        float x[8];
        if (row < NN) {
            const float* sp = (k0 < 128) ? (feat + (size_t)row * 128 + k0)
                                         : (hst  + (size_t)row * 128 + (k0 - 128));
            const float4 v0 = *(const float4*)sp;
            const float4 v1 = *(const float4*)(sp + 4);
            x[0] = v0.x; x[1] = v0.y; x[2] = v0.z; x[3] = v0.w;
            x[4] = v1.x; x[5] = v1.y; x[6] = v1.z; x[7] = v1.w;
        } else {
#pragma unroll
            for (int i = 0; i < 8; ++i) x[i] = 0.f;
        }
        bf16x8 hi, lo;
#pragma unroll
        for (int i = 0; i < 8; ++i) {
            const __bf16 hv = (__bf16)x[i];
            hi[i] = hv;
            lo[i] = (__bf16)(x[i] - (float)hv);
        }
        const int kt = k0 >> 5, fkh = (k0 >> 3) & 3;
        const size_t idx = ((size_t)(kt * 4 + fkh) * NNP + row) * 8;
        *(bf16x8*)(Aph + idx) = hi;
        *(bf16x8*)(Apl + idx) = lo;
    }
}

// ======================= GEMM1: logits -> rtab (fragment-packed, no LDS) =======================
__global__ __launch_bounds__(256) void gemm_rtab(
    const __bf16* __restrict__ Aph, const __bf16* __restrict__ Apl,
    const __bf16* __restrict__ B1h, const __bf16* __restrict__ B1l,
    const float* __restrict__ bias1, float* __restrict__ rtab)
{
    const int t = threadIdx.x, lane = t & 63, wid = t >> 6;
    const int m0 = blockIdx.x * 64;
    const int wm = (wid >> 1) * 32, wn = (wid & 1) * 64;
    const int fr = lane & 15, fkh = lane >> 4;

    f32x4 acc[2][4];
#pragma unroll
    for (int i = 0; i < 2; ++i)
#pragma unroll
        for (int j = 0; j < 4; ++j) acc[i][j] = (f32x4){0.f, 0.f, 0.f, 0.f};

    for (int kt = 0; kt < 8; ++kt) {
        const size_t ab = (size_t)(kt * 4 + fkh) * NNP;
        const size_t bb = (size_t)(kt * 4 + fkh) * 128;
        bf16x8 ah[2], al[2];
#pragma unroll
        for (int mf = 0; mf < 2; ++mf) {
            const size_t ro = (ab + m0 + wm + mf * 16 + fr) * 8;
            ah[mf] = *(const bf16x8*)(Aph + ro);
            al[mf] = *(const bf16x8*)(Apl + ro);
        }
#pragma unroll
        for (int nf = 0; nf < 4; ++nf) {
            const size_t ro = (bb + wn + nf * 16 + fr) * 8;
            const bf16x8 bh = *(const bf16x8*)(B1h + ro);
            const bf16x8 bl = *(const bf16x8*)(B1l + ro);
#pragma unroll
            for (int mf = 0; mf < 2; ++mf) {
                acc[mf][nf] = __builtin_amdgcn_mfma_f32_16x16x32_bf16(ah[mf], bh, acc[mf][nf], 0, 0, 0);
                acc[mf][nf] = __builtin_amdgcn_mfma_f32_16x16x32_bf16(al[mf], bh, acc[mf][nf], 0, 0, 0);
                acc[mf][nf] = __builtin_amdgcn_mfma_f32_16x16x32_bf16(ah[mf], bl, acc[mf][nf], 0, 0, 0);
            }
        }
    }

    // epilogue: pair (nf, nf+2) in same lane -> r = exp(l1-l0)
#pragma unroll
    for (int nf = 0; nf < 2; ++nf) {
        const int c0 = wn + nf * 16 + fr;
        const float b0 = bias1[c0], b1 = bias1[c0 + 32];
        const int j = (wid & 1) * 32 + nf * 16 + fr;
#pragma unroll
        for (int mf = 0; mf < 2; ++mf)
#pragma unroll
            for (int rr = 0; rr < 4; ++rr) {
                const int gr = m0 + wm + mf * 16 + (lane >> 4) * 4 + rr;
                if (gr < NN)
                    rtab[(size_t)gr * 64 + j] =
                        expf((acc[mf][nf + 2][rr] + b1) - (acc[mf][nf][rr] + b0));
            }
    }
}

// ======================= edge kernel: 16 edges per wave =======================
#define EPW 16
__global__ __launch_bounds__(256) void edge_k(
    const float* __restrict__ u, const int* __restrict__ src,
    const int* __restrict__ dst, const float* __restrict__ rtab,
    unsigned long long* __restrict__ masks)
{
    const int wv = __builtin_amdgcn_readfirstlane(blockIdx.x * 4 + (threadIdx.x >> 6));
    const int lane = threadIdx.x & 63;
    const int e0 = wv * EPW;

    float2 uu[EPW];
    float  rr[EPW];
    int    dd[EPW];
#pragma unroll
    for (int i = 0; i < EPW; ++i) {
        const int e = e0 + i;
        uu[i] = *(const float2*)(u + (size_t)e * 128 + lane * 2);
        rr[i] = rtab[(size_t)src[e] * 64 + lane];
        dd[i] = dst[e];
    }
#pragma unroll
    for (int i = 0; i < EPW; ++i) {
        const float a0 = GEPS - logf(uu[i].x + GEPS);
        const float a1 = GEPS - logf(uu[i].y + GEPS);
        const unsigned long long mone = __ballot(rr[i] * a0 > a1);
        if (lane == 0) {
            atomicOr(&masks[(size_t)dd[i] * 2 + 1], mone);
            atomicOr(&masks[(size_t)dd[i] * 2 + 0], ~mone);
        }
    }
}

// ======================= GEMM2: gates (fragment-packed, no LDS) + GRU epilogue =======================
// XCD-grouped grid (R13 lesson applied to R10 base): the 4 nb-blocks sharing an A-tile
// get the same bid%8 -> same XCD -> A-tile HBM-fetched once, shared via that XCD's L2.
__global__ __launch_bounds__(256) void gemm_gates(
    const __bf16* __restrict__ Aph, const __bf16* __restrict__ Apl,
    const __bf16* __restrict__ B2h, const __bf16* __restrict__ B2l,
    const float* __restrict__ bias2, const unsigned long long* __restrict__ masks,
    const float* __restrict__ W_comb, const float* __restrict__ h,
    float* __restrict__ out)
{
    const int bid = blockIdx.x;
    const int g = bid & 7;
    const int inner = bid >> 3;
    const int nb = inner & 3;
    const int mrow = (inner >> 2) * 8 + g;
    if (mrow >= NNP / 128) return;
    const int m0 = mrow * 128;

    const int t = threadIdx.x, lane = t & 63, wid = t >> 6;
    const int wm = wid * 32;
    const int fr = lane & 15, fkh = lane >> 4;

    f32x4 acc[2][8];
#pragma unroll
    for (int i = 0; i < 2; ++i)
#pragma unroll
        for (int j = 0; j < 8; ++j) acc[i][j] = (f32x4){0.f, 0.f, 0.f, 0.f};

    for (int kt = 0; kt < 8; ++kt) {
        const size_t ab = (size_t)(kt * 4 + fkh) * NNP;
        const size_t bb = (size_t)(kt * 4 + fkh) * 512;
        bf16x8 ah[2], al[2];
#pragma unroll
        for (int mf = 0; mf < 2; ++mf) {
            const size_t ro = (ab + m0 + wm + mf * 16 + fr) * 8;
            ah[mf] = *(const bf16x8*)(Aph + ro);
            al[mf] = *(const bf16x8*)(Apl + ro);
        }
#pragma unroll
        for (int nf = 0; nf < 8; ++nf) {
            const size_t ro = (bb + nb * 128 + nf * 16 + fr) * 8;
            const bf16x8 bh = *(const bf16x8*)(B2h + ro);
            const bf16x8 bl = *(const bf16x8*)(B2l + ro);
#pragma unroll
            for (int mf = 0; mf < 2; ++mf) {
                acc[mf][nf] = __builtin_amdgcn_mfma_f32_16x16x32_bf16(ah[mf], bh, acc[mf][nf], 0, 0, 0);
                acc[mf][nf] = __builtin_amdgcn_mfma_f32_16x16x32_bf16(al[mf], bh, acc[mf][nf], 0, 0, 0);
                acc[mf][nf] = __builtin_amdgcn_mfma_f32_16x16x32_bf16(ah[mf], bl, acc[mf][nf], 0, 0, 0);
            }
        }
    }

    // ---- fused GRU epilogue ----
    float bia[8];
#pragma unroll
    for (int nf = 0; nf < 8; ++nf) bia[nf] = bias2[nb * 128 + nf * 16 + fr];

#pragma unroll
    for (int mf = 0; mf < 2; ++mf)
#pragma unroll
        for (int rr = 0; rr < 4; ++rr) {
            const int gr = m0 + wm + mf * 16 + (lane >> 4) * 4 + rr;
            if (gr >= NN) continue;
            const unsigned long long ze = ~masks[(size_t)gr * 2 + 0];
            const unsigned long long zo = ~masks[(size_t)gr * 2 + 1];
#pragma unroll
            for (int jh = 0; jh < 2; ++jh) {
                const int j = nb * 32 + jh * 16 + fr;
                float rp = acc[mf][0 + jh][rr] + bia[0 + jh];
                float zp = acc[mf][2 + jh][rr] + bia[2 + jh];
                float ip = acc[mf][4 + jh][rr] + bia[4 + jh];
                float hp = acc[mf][6 + jh][rr] + bia[6 + jh];
                if (ze | zo) {
                    unsigned long long bz = ze;
#pragma unroll 1
                    while (bz) {
                        const int k = __builtin_ctzll(bz); bz &= bz - 1;
                        const int bit = 2 * k;
                        rp -= W_comb[(size_t)j * 128 + bit];
                        zp -= W_comb[(size_t)(128 + j) * 128 + bit];
                        ip -= W_comb[(size_t)(256 + j) * 128 + bit];
                    }
                    bz = zo;
#pragma unroll 1
                    while (bz) {
                        const int k = __builtin_ctzll(bz); bz &= bz - 1;
                        const int bit = 2 * k + 1;
                        rp -= W_comb[(size_t)j * 128 + bit];
                        zp -= W_comb[(size_t)(128 + j) * 128 + bit];
                        ip -= W_comb[(size_t)(256 + j) * 128 + bit];
                    }
                }
                const float hv = h[(size_t)gr * 128 + j];
                const float rg = 1.f / (1.f + expf(-rp));
                const float zg = 1.f / (1.f + expf(-zp));
                const float nv = tanhf(ip + rg * hp);
                const float o = (1.f - zg) * nv + zg * hv;
                out[(size_t)gr * 128 + j] = o;
                out[(size_t)(NN + gr) * 128 + j] = o;
            }
        }
}

extern "C" void kernel_launch(void* const* d_in, const int* in_sizes, int n_in,
                              void* d_out, int out_size, void* d_ws, size_t ws_size,
                              hipStream_t stream) {
    const float* feat  = (const float*)d_in[0];
    const float* h     = (const float*)d_in[1];
    const int*   src   = (const int*)d_in[2];
    const int*   dst   = (const int*)d_in[3];
    const float* u     = (const float*)d_in[4];
    const float* W_enc = (const float*)d_in[5];
    const float* b_enc = (const float*)d_in[6];
    const float* W_dec = (const float*)d_in[7];
    const float* b_dec = (const float*)d_in[8];
    const float* W_ih  = (const float*)d_in[9];
    const float* W_hh  = (const float*)d_in[10];
    const float* b_ih  = (const float*)d_in[11];
    const float* b_hh  = (const float*)d_in[12];
    float* out = (float*)d_out;
    (void)in_sizes; (void)n_in; (void)out_size; (void)ws_size;

    char* ws = (char*)d_ws;
    float*              rtab   = (float*)(ws + 0);                    // 5,120,000 B
    unsigned long long* masks  = (unsigned long long*)(ws + 5120000); //   320,000 B
    __bf16*             B1h    = (__bf16*)(ws + 5440000);             //    65,536 B
    __bf16*             B1l    = (__bf16*)(ws + 5505536);             //    65,536 B
    __bf16*             B2h    = (__bf16*)(ws + 5571072);             //   262,144 B
    __bf16*             B2l    = (__bf16*)(ws + 5833216);             //   262,144 B
    float*              bias1  = (float*)(ws + 6095360);              //       512 B
    float*              bias2  = (float*)(ws + 6095872);              //     2,048 B
    float*              W_comb = (float*)(ws + 6097920);              //   196,608 B
    __bf16*             Aph    = (__bf16*)(ws + 6294528);             // 10,289,152 B
    __bf16*             Apl    = (__bf16*)(ws + 16583680);            // 10,289,152 B

    // pack weights + split A (fragment order) + fold biases + zero masks
    prep_k<<<914 + NNP / 8, 256, 0, stream>>>(
        feat, h, W_enc, b_enc, W_dec, b_dec, W_ih, W_hh, b_ih, b_hh,
        B1h, B1l, B2h, B2l, bias1, bias2, W_comb, (ulonglong2*)masks, Aph, Apl);

    // logits GEMM -> rtab (M=20000, N=128, K=256)
    gemm_rtab<<<313, 256, 0, stream>>>(Aph, Apl, B1h, B1l, bias1, rtab);

    // per-edge gumbel argmax -> OR masks
    edge_k<<<NE / (4 * EPW), 256, 0, stream>>>(u, src, dst, rtab, masks);

    // gate GEMM + fused GRU epilogue -> out (M=20000, N=512, K=256), XCD-grouped grid
    gemm_gates<<<640, 256, 0, stream>>>(Aph, Apl, B2h, B2l, bias2, masks, W_comb, h, out);
}

// Round 15
// 103.761 us; speedup vs baseline: 9.8160x; 1.0246x over previous
//
#include <hip/hip_runtime.h>
#include <stdint.h>

#define NN   20000
#define NNP  20096   // padded rows (157*128)
#define NE   320000
#define GEPS 1e-10f

typedef __attribute__((ext_vector_type(8))) __bf16 bf16x8;
typedef __attribute__((ext_vector_type(4))) float f32x4;

// fast transcendentals (HW v_exp/v_log based): rel err ~2^-21, safe for
// gumbel decisions (margin err ~1e-6) and gate outputs (<=1e-6 shift).
__device__ __forceinline__ float fsigmoid(float x) { return 1.f / (1.f + __expf(-x)); }
__device__ __forceinline__ float ftanh(float x)    { return 1.f - 2.f / (__expf(2.f * x) + 1.f); }

// Fragment-order layout: chunk (kt,fkh) of row r lives at ((kt*4+fkh)*ROWS + r)*8.
// A wave's MFMA fragment load (fr=lane&15, fkh=lane>>4) is then 4x contiguous 256B.

// ======================= prep: pack weights + split A + zero masks =======================
__global__ __launch_bounds__(256) void prep_k(
    const float* __restrict__ feat,  const float* __restrict__ hst,
    const float* __restrict__ W_enc, const float* __restrict__ b_enc,
    const float* __restrict__ W_dec, const float* __restrict__ b_dec,
    const float* __restrict__ W_ih,  const float* __restrict__ W_hh,
    const float* __restrict__ b_ih,  const float* __restrict__ b_hh,
    __bf16* __restrict__ B1h, __bf16* __restrict__ B1l,
    __bf16* __restrict__ B2h, __bf16* __restrict__ B2l,
    float* __restrict__ bias1, float* __restrict__ bias2,
    float* __restrict__ W_comb, ulonglong2* __restrict__ mask2,
    __bf16* __restrict__ Aph, __bf16* __restrict__ Apl)
{
    const int b = blockIdx.x, t = threadIdx.x;
    if (b < 128) {
        const int src = (b >> 6) * 64 + (b & 31) * 2 + ((b >> 5) & 1);
        const float v = W_enc[src * 256 + t];
        const __bf16 hi = (__bf16)v;
        const int kt = t >> 5, fkh = (t >> 3) & 3, e = t & 7;
        const size_t idx = ((size_t)(kt * 4 + fkh) * 128 + b) * 8 + e;
        B1h[idx] = hi;
        B1l[idx] = (__bf16)(v - (float)hi);
    } else if (b < 640) {
        const int r2 = b - 128;
        const int nb = r2 >> 7, rem = r2 & 127, g = rem >> 5, jj = rem & 31;
        const int j = nb * 32 + jj;
        const int k = t;
        float v;
        if (g == 0)      v = (k < 128) ? W_ih[j * 256 + k]         : W_hh[j * 128 + (k - 128)];
        else if (g == 1) v = (k < 128) ? W_ih[(128 + j) * 256 + k] : W_hh[(128 + j) * 128 + (k - 128)];
        else if (g == 2) v = (k < 128) ? W_ih[(256 + j) * 256 + k] : 0.f;
        else             v = (k < 128) ? 0.f                       : W_hh[(256 + j) * 128 + (k - 128)];
        const __bf16 hi = (__bf16)v;
        const int kt = t >> 5, fkh = (t >> 3) & 3, e = t & 7;
        const size_t idx = ((size_t)(kt * 4 + fkh) * 512 + r2) * 8 + e;
        B2h[idx] = hi;
        B2l[idx] = (__bf16)(v - (float)hi);
    } else if (b < 832) {
        const int idx = (b - 640) * 256 + t;
        const int o = idx >> 7, k = idx & 127;
        float s = 0.f;
        for (int l = 0; l < 128; ++l)
            s += W_ih[o * 256 + 128 + l] * W_dec[l * 128 + k];
        W_comb[idx] = s;
    } else if (b < 835) {
        __shared__ float bd[128];
        if (t < 128) {
            float s = b_dec[t];
            for (int k = 0; k < 128; ++k) s += W_dec[t * 128 + k];
            bd[t] = s;
        }
        __syncthreads();
        const int g = (b - 832) * 256 + t;   // 0..767
        if (g < 128) {
            bias1[g] = b_enc[(g >> 6) * 64 + (g & 31) * 2 + ((g >> 5) & 1)];
        } else if (g < 640) {
            const int c2 = g - 128;
            const int nb = c2 >> 7, rem = c2 & 127, gg = rem >> 5, jj = rem & 31;
            const int j = nb * 32 + jj;
            float v;
            if (gg == 3) v = b_hh[256 + j];
            else {
                const int o = gg * 128 + j;
                float s = (gg == 2) ? b_ih[o] : (b_ih[o] + b_hh[o]);
                for (int l = 0; l < 128; ++l) s += W_ih[o * 256 + 128 + l] * bd[l];
                v = s;
            }
            bias2[c2] = v;
        }
    } else if (b < 914) {
        const int i = (b - 835) * 256 + t;
        if (i < NN) mask2[i] = make_ulonglong2(0ull, 0ull);
    } else {
        // A split into fragment order: 8 rows/block, 32 chunks of 8 elems
        const int blk = b - 914;              // 0..2511
        const int row = blk * 8 + (t & 7);
        const int k0  = (t >> 3) * 8;         // 0..248
        float x[8];
        if (row < NN) {
            const float* sp = (k0 < 128) ? (feat + (size_t)row * 128 + k0)
                                         : (hst  + (size_t)row * 128 + (k0 - 128));
            const float4 v0 = *(const float4*)sp;
            const float4 v1 = *(const float4*)(sp + 4);
            x[0] = v0.x; x[1] = v0.y; x[2] = v0.z; x[3] = v0.w;
            x[4] = v1.x; x[5] = v1.y; x[6] = v1.z; x[7] = v1.w;
        } else {
#pragma unroll
            for (int i = 0; i < 8; ++i) x[i] = 0.f;
        }
        bf16x8 hi, lo;
#pragma unroll
        for (int i = 0; i < 8; ++i) {
            const __bf16 hv = (__bf16)x[i];
            hi[i] = hv;
            lo[i] = (__bf16)(x[i] - (float)hv);
        }
        const int kt = k0 >> 5, fkh = (k0 >> 3) & 3;
        const size_t idx = ((size_t)(kt * 4 + fkh) * NNP + row) * 8;
        *(bf16x8*)(Aph + idx) = hi;
        *(bf16x8*)(Apl + idx) = lo;
    }
}

// ======================= GEMM1: logits -> rtab (fragment-packed, no LDS) =======================
__global__ __launch_bounds__(256) void gemm_rtab(
    const __bf16* __restrict__ Aph, const __bf16* __restrict__ Apl,
    const __bf16* __restrict__ B1h, const __bf16* __restrict__ B1l,
    const float* __restrict__ bias1, float* __restrict__ rtab)
{
    const int t = threadIdx.x, lane = t & 63, wid = t >> 6;
    const int m0 = blockIdx.x * 64;
    const int wm = (wid >> 1) * 32, wn = (wid & 1) * 64;
    const int fr = lane & 15, fkh = lane >> 4;

    f32x4 acc[2][4];
#pragma unroll
    for (int i = 0; i < 2; ++i)
#pragma unroll
        for (int j = 0; j < 4; ++j) acc[i][j] = (f32x4){0.f, 0.f, 0.f, 0.f};

    for (int kt = 0; kt < 8; ++kt) {
        const size_t ab = (size_t)(kt * 4 + fkh) * NNP;
        const size_t bb = (size_t)(kt * 4 + fkh) * 128;
        bf16x8 ah[2], al[2];
#pragma unroll
        for (int mf = 0; mf < 2; ++mf) {
            const size_t ro = (ab + m0 + wm + mf * 16 + fr) * 8;
            ah[mf] = *(const bf16x8*)(Aph + ro);
            al[mf] = *(const bf16x8*)(Apl + ro);
        }
#pragma unroll
        for (int nf = 0; nf < 4; ++nf) {
            const size_t ro = (bb + wn + nf * 16 + fr) * 8;
            const bf16x8 bh = *(const bf16x8*)(B1h + ro);
            const bf16x8 bl = *(const bf16x8*)(B1l + ro);
#pragma unroll
            for (int mf = 0; mf < 2; ++mf) {
                acc[mf][nf] = __builtin_amdgcn_mfma_f32_16x16x32_bf16(ah[mf], bh, acc[mf][nf], 0, 0, 0);
                acc[mf][nf] = __builtin_amdgcn_mfma_f32_16x16x32_bf16(al[mf], bh, acc[mf][nf], 0, 0, 0);
                acc[mf][nf] = __builtin_amdgcn_mfma_f32_16x16x32_bf16(ah[mf], bl, acc[mf][nf], 0, 0, 0);
            }
        }
    }

    // epilogue: pair (nf, nf+2) in same lane -> r = exp(l1-l0)
#pragma unroll
    for (int nf = 0; nf < 2; ++nf) {
        const int c0 = wn + nf * 16 + fr;
        const float b0 = bias1[c0], b1 = bias1[c0 + 32];
        const int j = (wid & 1) * 32 + nf * 16 + fr;
#pragma unroll
        for (int mf = 0; mf < 2; ++mf)
#pragma unroll
            for (int rr = 0; rr < 4; ++rr) {
                const int gr = m0 + wm + mf * 16 + (lane >> 4) * 4 + rr;
                if (gr < NN)
                    rtab[(size_t)gr * 64 + j] =
                        __expf((acc[mf][nf + 2][rr] + b1) - (acc[mf][nf][rr] + b0));
            }
    }
}

// ======================= edge kernel: 16 edges per wave =======================
#define EPW 16
__global__ __launch_bounds__(256) void edge_k(
    const float* __restrict__ u, const int* __restrict__ src,
    const int* __restrict__ dst, const float* __restrict__ rtab,
    unsigned long long* __restrict__ masks)
{
    const int wv = __builtin_amdgcn_readfirstlane(blockIdx.x * 4 + (threadIdx.x >> 6));
    const int lane = threadIdx.x & 63;
    const int e0 = wv * EPW;

    float2 uu[EPW];
    float  rr[EPW];
    int    dd[EPW];
#pragma unroll
    for (int i = 0; i < EPW; ++i) {
        const int e = e0 + i;
        uu[i] = *(const float2*)(u + (size_t)e * 128 + lane * 2);
        rr[i] = rtab[(size_t)src[e] * 64 + lane];
        dd[i] = dst[e];
    }
#pragma unroll
    for (int i = 0; i < EPW; ++i) {
        const float a0 = GEPS - __logf(uu[i].x + GEPS);
        const float a1 = GEPS - __logf(uu[i].y + GEPS);
        const unsigned long long mone = __ballot(rr[i] * a0 > a1);
        if (lane == 0) {
            atomicOr(&masks[(size_t)dd[i] * 2 + 1], mone);
            atomicOr(&masks[(size_t)dd[i] * 2 + 0], ~mone);
        }
    }
}

// ======================= GEMM2: gates (fragment-packed, no LDS) + GRU epilogue =======================
// XCD-grouped grid: the 4 nb-blocks sharing an A-tile get the same bid%8 -> same XCD L2.
__global__ __launch_bounds__(256) void gemm_gates(
    const __bf16* __restrict__ Aph, const __bf16* __restrict__ Apl,
    const __bf16* __restrict__ B2h, const __bf16* __restrict__ B2l,
    const float* __restrict__ bias2, const unsigned long long* __restrict__ masks,
    const float* __restrict__ W_comb, const float* __restrict__ h,
    float* __restrict__ out)
{
    const int bid = blockIdx.x;
    const int g = bid & 7;
    const int inner = bid >> 3;
    const int nb = inner & 3;
    const int mrow = (inner >> 2) * 8 + g;
    if (mrow >= NNP / 128) return;
    const int m0 = mrow * 128;

    const int t = threadIdx.x, lane = t & 63, wid = t >> 6;
    const int wm = wid * 32;
    const int fr = lane & 15, fkh = lane >> 4;

    f32x4 acc[2][8];
#pragma unroll
    for (int i = 0; i < 2; ++i)
#pragma unroll
        for (int j = 0; j < 8; ++j) acc[i][j] = (f32x4){0.f, 0.f, 0.f, 0.f};

    for (int kt = 0; kt < 8; ++kt) {
        const size_t ab = (size_t)(kt * 4 + fkh) * NNP;
        const size_t bb = (size_t)(kt * 4 + fkh) * 512;
        bf16x8 ah[2], al[2];
#pragma unroll
        for (int mf = 0; mf < 2; ++mf) {
            const size_t ro = (ab + m0 + wm + mf * 16 + fr) * 8;
            ah[mf] = *(const bf16x8*)(Aph + ro);
            al[mf] = *(const bf16x8*)(Apl + ro);
        }
#pragma unroll
        for (int nf = 0; nf < 8; ++nf) {
            const size_t ro = (bb + nb * 128 + nf * 16 + fr) * 8;
            const bf16x8 bh = *(const bf16x8*)(B2h + ro);
            const bf16x8 bl = *(const bf16x8*)(B2l + ro);
#pragma unroll
            for (int mf = 0; mf < 2; ++mf) {
                acc[mf][nf] = __builtin_amdgcn_mfma_f32_16x16x32_bf16(ah[mf], bh, acc[mf][nf], 0, 0, 0);
                acc[mf][nf] = __builtin_amdgcn_mfma_f32_16x16x32_bf16(al[mf], bh, acc[mf][nf], 0, 0, 0);
                acc[mf][nf] = __builtin_amdgcn_mfma_f32_16x16x32_bf16(ah[mf], bl, acc[mf][nf], 0, 0, 0);
            }
        }
    }

    // ---- fused GRU epilogue ----
    float bia[8];
#pragma unroll
    for (int nf = 0; nf < 8; ++nf) bia[nf] = bias2[nb * 128 + nf * 16 + fr];

#pragma unroll
    for (int mf = 0; mf < 2; ++mf)
#pragma unroll
        for (int rr = 0; rr < 4; ++rr) {
            const int gr = m0 + wm + mf * 16 + (lane >> 4) * 4 + rr;
            if (gr >= NN) continue;
            const unsigned long long ze = ~masks[(size_t)gr * 2 + 0];
            const unsigned long long zo = ~masks[(size_t)gr * 2 + 1];
#pragma unroll
            for (int jh = 0; jh < 2; ++jh) {
                const int j = nb * 32 + jh * 16 + fr;
                float rp = acc[mf][0 + jh][rr] + bia[0 + jh];
                float zp = acc[mf][2 + jh][rr] + bia[2 + jh];
                float ip = acc[mf][4 + jh][rr] + bia[4 + jh];
                float hp = acc[mf][6 + jh][rr] + bia[6 + jh];
                if (ze | zo) {
                    unsigned long long bz = ze;
#pragma unroll 1
                    while (bz) {
                        const int k = __builtin_ctzll(bz); bz &= bz - 1;
                        const int bit = 2 * k;
                        rp -= W_comb[(size_t)j * 128 + bit];
                        zp -= W_comb[(size_t)(128 + j) * 128 + bit];
                        ip -= W_comb[(size_t)(256 + j) * 128 + bit];
                    }
                    bz = zo;
#pragma unroll 1
                    while (bz) {
                        const int k = __builtin_ctzll(bz); bz &= bz - 1;
                        const int bit = 2 * k + 1;
                        rp -= W_comb[(size_t)j * 128 + bit];
                        zp -= W_comb[(size_t)(128 + j) * 128 + bit];
                        ip -= W_comb[(size_t)(256 + j) * 128 + bit];
                    }
                }
                const float hv = h[(size_t)gr * 128 + j];
                const float rg = fsigmoid(rp);
                const float zg = fsigmoid(zp);
                const float nv = ftanh(ip + rg * hp);
                const float o = (1.f - zg) * nv + zg * hv;
                out[(size_t)gr * 128 + j] = o;
                out[(size_t)(NN + gr) * 128 + j] = o;
            }
        }
}

extern "C" void kernel_launch(void* const* d_in, const int* in_sizes, int n_in,
                              void* d_out, int out_size, void* d_ws, size_t ws_size,
                              hipStream_t stream) {
    const float* feat  = (const float*)d_in[0];
    const float* h     = (const float*)d_in[1];
    const int*   src   = (const int*)d_in[2];
    const int*   dst   = (const int*)d_in[3];
    const float* u     = (const float*)d_in[4];
    const float* W_enc = (const float*)d_in[5];
    const float* b_enc = (const float*)d_in[6];
    const float* W_dec = (const float*)d_in[7];
    const float* b_dec = (const float*)d_in[8];
    const float* W_ih  = (const float*)d_in[9];
    const float* W_hh  = (const float*)d_in[10];
    const float* b_ih  = (const float*)d_in[11];
    const float* b_hh  = (const float*)d_in[12];
    float* out = (float*)d_out;
    (void)in_sizes; (void)n_in; (void)out_size; (void)ws_size;

    char* ws = (char*)d_ws;
    float*              rtab   = (float*)(ws + 0);                    // 5,120,000 B
    unsigned long long* masks  = (unsigned long long*)(ws + 5120000); //   320,000 B
    __bf16*             B1h    = (__bf16*)(ws + 5440000);             //    65,536 B
    __bf16*             B1l    = (__bf16*)(ws + 5505536);             //    65,536 B
    __bf16*             B2h    = (__bf16*)(ws + 5571072);             //   262,144 B
    __bf16*             B2l    = (__bf16*)(ws + 5833216);             //   262,144 B
    float*              bias1  = (float*)(ws + 6095360);              //       512 B
    float*              bias2  = (float*)(ws + 6095872);              //     2,048 B
    float*              W_comb = (float*)(ws + 6097920);              //   196,608 B
    __bf16*             Aph    = (__bf16*)(ws + 6294528);             // 10,289,152 B
    __bf16*             Apl    = (__bf16*)(ws + 16583680);            // 10,289,152 B

    // pack weights + split A (fragment order) + fold biases + zero masks
    prep_k<<<914 + NNP / 8, 256, 0, stream>>>(
        feat, h, W_enc, b_enc, W_dec, b_dec, W_ih, W_hh, b_ih, b_hh,
        B1h, B1l, B2h, B2l, bias1, bias2, W_comb, (ulonglong2*)masks, Aph, Apl);

    // logits GEMM -> rtab (M=20000, N=128, K=256)
    gemm_rtab<<<313, 256, 0, stream>>>(Aph, Apl, B1h, B1l, bias1, rtab);

    // per-edge gumbel argmax -> OR masks
    edge_k<<<NE / (4 * EPW), 256, 0, stream>>>(u, src, dst, rtab, masks);

    // gate GEMM + fused GRU epilogue -> out (M=20000, N=512, K=256), XCD-grouped grid
    gemm_gates<<<640, 256, 0, stream>>>(Aph, Apl, B2h, B2l, bias2, masks, W_comb, h, out);
}

// Round 18
// 92.680 us; speedup vs baseline: 10.9897x; 1.1196x over previous
//
#include <hip/hip_runtime.h>
#include <stdint.h>

#define NN   20000
#define NNP  20096   // padded rows (157*128)
#define NE   320000
#define GEPS 1e-10f

typedef __attribute__((ext_vector_type(8))) __bf16 bf16x8;
typedef __attribute__((ext_vector_type(4))) float f32x4;

__device__ __forceinline__ float fsigmoid(float x) { return 1.f / (1.f + __expf(-x)); }
__device__ __forceinline__ float ftanh(float x)    { return 1.f - 2.f / (__expf(2.f * x) + 1.f); }

// Fragment-order layout: chunk (kt,fkh) of row r lives at ((kt*4+fkh)*ROWS + r)*8.

// ======================= prep: pack weights + split A + zero masks =======================
__global__ __launch_bounds__(256) void prep_k(
    const float* __restrict__ feat,  const float* __restrict__ hst,
    const float* __restrict__ W_enc, const float* __restrict__ b_enc,
    const float* __restrict__ W_dec, const float* __restrict__ b_dec,
    const float* __restrict__ W_ih,  const float* __restrict__ W_hh,
    const float* __restrict__ b_ih,  const float* __restrict__ b_hh,
    __bf16* __restrict__ B1h, __bf16* __restrict__ B1l,
    __bf16* __restrict__ B2h, __bf16* __restrict__ B2l,
    float* __restrict__ bias1, float* __restrict__ bias2,
    float* __restrict__ W_comb, ulonglong2* __restrict__ mask2,
    __bf16* __restrict__ Aph, __bf16* __restrict__ Apl)
{
    const int b = blockIdx.x, t = threadIdx.x;
    if (b < 128) {
        const int src = (b >> 6) * 64 + (b & 31) * 2 + ((b >> 5) & 1);
        const float v = W_enc[src * 256 + t];
        const __bf16 hi = (__bf16)v;
        const int kt = t >> 5, fkh = (t >> 3) & 3, e = t & 7;
        const size_t idx = ((size_t)(kt * 4 + fkh) * 128 + b) * 8 + e;
        B1h[idx] = hi;
        B1l[idx] = (__bf16)(v - (float)hi);
    } else if (b < 640) {
        const int r2 = b - 128;
        const int nb = r2 >> 7, rem = r2 & 127, g = rem >> 5, jj = rem & 31;
        const int j = nb * 32 + jj;
        const int k = t;
        float v;
        if (g == 0)      v = (k < 128) ? W_ih[j * 256 + k]         : W_hh[j * 128 + (k - 128)];
        else if (g == 1) v = (k < 128) ? W_ih[(128 + j) * 256 + k] : W_hh[(128 + j) * 128 + (k - 128)];
        else if (g == 2) v = (k < 128) ? W_ih[(256 + j) * 256 + k] : 0.f;
        else             v = (k < 128) ? 0.f                       : W_hh[(256 + j) * 128 + (k - 128)];
        const __bf16 hi = (__bf16)v;
        const int kt = t >> 5, fkh = (t >> 3) & 3, e = t & 7;
        const size_t idx = ((size_t)(kt * 4 + fkh) * 512 + r2) * 8 + e;
        B2h[idx] = hi;
        B2l[idx] = (__bf16)(v - (float)hi);
    } else if (b < 832) {
        const int idx = (b - 640) * 256 + t;
        const int o = idx >> 7, k = idx & 127;
        float s = 0.f;
        for (int l = 0; l < 128; ++l)
            s += W_ih[o * 256 + 128 + l] * W_dec[l * 128 + k];
        W_comb[idx] = s;
    } else if (b < 835) {
        __shared__ float bd[128];
        if (t < 128) {
            float s = b_dec[t];
            for (int k = 0; k < 128; ++k) s += W_dec[t * 128 + k];
            bd[t] = s;
        }
        __syncthreads();
        const int g = (b - 832) * 256 + t;   // 0..767
        if (g < 128) {
            bias1[g] = b_enc[(g >> 6) * 64 + (g & 31) * 2 + ((g >> 5) & 1)];
        } else if (g < 640) {
            const int c2 = g - 128;
            const int nb = c2 >> 7, rem = c2 & 127, gg = rem >> 5, jj = rem & 31;
            const int j = nb * 32 + jj;
            float v;
            if (gg == 3) v = b_hh[256 + j];
            else {
                const int o = gg * 128 + j;
                float s = (gg == 2) ? b_ih[o] : (b_ih[o] + b_hh[o]);
                for (int l = 0; l < 128; ++l) s += W_ih[o * 256 + 128 + l] * bd[l];
                v = s;
            }
            bias2[c2] = v;
        }
    } else if (b < 914) {
        const int i = (b - 835) * 256 + t;
        if (i < NN) mask2[i] = make_ulonglong2(0ull, 0ull);
    } else {
        // A split into fragment order: 8 rows/block, 32 chunks of 8 elems
        const int blk = b - 914;              // 0..2511
        const int row = blk * 8 + (t & 7);
        const int k0  = (t >> 3) * 8;         // 0..248
        float x[8];
        if (row < NN) {
            const float* sp = (k0 < 128) ? (feat + (size_t)row * 128 + k0)
                                         : (hst  + (size_t)row * 128 + (k0 - 128));
            const float4 v0 = *(const float4*)sp;
            const float4 v1 = *(const float4*)(sp + 4);
            x[0] = v0.x; x[1] = v0.y; x[2] = v0.z; x[3] = v0.w;
            x[4] = v1.x; x[5] = v1.y; x[6] = v1.z; x[7] = v1.w;
        } else {
#pragma unroll
            for (int i = 0; i < 8; ++i) x[i] = 0.f;
        }
        bf16x8 hi, lo;
#pragma unroll
        for (int i = 0; i < 8; ++i) {
            const __bf16 hv = (__bf16)x[i];
            hi[i] = hv;
            lo[i] = (__bf16)(x[i] - (float)hv);
        }
        const int kt = k0 >> 5, fkh = (k0 >> 3) & 3;
        const size_t idx = ((size_t)(kt * 4 + fkh) * NNP + row) * 8;
        *(bf16x8*)(Aph + idx) = hi;
        *(bf16x8*)(Apl + idx) = lo;
    }
}

// ======================= GEMM1: logits -> rtab (M-tile 32, 628 blocks) =======================
__global__ __launch_bounds__(256) void gemm_rtab(
    const __bf16* __restrict__ Aph, const __bf16* __restrict__ Apl,
    const __bf16* __restrict__ B1h, const __bf16* __restrict__ B1l,
    const float* __restrict__ bias1, float* __restrict__ rtab)
{
    const int t = threadIdx.x, lane = t & 63, wid = t >> 6;
    const int m0 = blockIdx.x * 32;
    const int wm = (wid & 1) * 16;        // row half (1 mf)
    const int cgn = wid >> 1;             // col half
    const int wn = cgn * 64;
    const int fr = lane & 15, fkh = lane >> 4;

    f32x4 acc[4];
#pragma unroll
    for (int j = 0; j < 4; ++j) acc[j] = (f32x4){0.f, 0.f, 0.f, 0.f};

    for (int kt = 0; kt < 8; ++kt) {
        const size_t ab = (size_t)(kt * 4 + fkh) * NNP;
        const size_t bb = (size_t)(kt * 4 + fkh) * 128;
        const size_t ro = (ab + m0 + wm + fr) * 8;
        const bf16x8 ah = *(const bf16x8*)(Aph + ro);
        const bf16x8 al = *(const bf16x8*)(Apl + ro);
#pragma unroll
        for (int nf = 0; nf < 4; ++nf) {
            const size_t rb = (bb + wn + nf * 16 + fr) * 8;
            const bf16x8 bh = *(const bf16x8*)(B1h + rb);
            const bf16x8 bl = *(const bf16x8*)(B1l + rb);
            acc[nf] = __builtin_amdgcn_mfma_f32_16x16x32_bf16(ah, bh, acc[nf], 0, 0, 0);
            acc[nf] = __builtin_amdgcn_mfma_f32_16x16x32_bf16(al, bh, acc[nf], 0, 0, 0);
            acc[nf] = __builtin_amdgcn_mfma_f32_16x16x32_bf16(ah, bl, acc[nf], 0, 0, 0);
        }
    }

    // epilogue: pair (nf, nf+2) in same lane -> r = exp(l1-l0)
#pragma unroll
    for (int nf = 0; nf < 2; ++nf) {
        const int c0 = wn + nf * 16 + fr;
        const float b0 = bias1[c0], b1 = bias1[c0 + 32];
        const int j = cgn * 32 + nf * 16 + fr;
#pragma unroll
        for (int rr = 0; rr < 4; ++rr) {
            const int gr = m0 + wm + (lane >> 4) * 4 + rr;
            if (gr < NN)
                rtab[(size_t)gr * 64 + j] =
                    __expf((acc[nf + 2][rr] + b1) - (acc[nf][rr] + b0));
        }
    }
}

// ======================= edge kernel: 16 edges per wave =======================
#define EPW 16
__global__ __launch_bounds__(256) void edge_k(
    const float* __restrict__ u, const int* __restrict__ src,
    const int* __restrict__ dst, const float* __restrict__ rtab,
    unsigned long long* __restrict__ masks)
{
    const int wv = __builtin_amdgcn_readfirstlane(blockIdx.x * 4 + (threadIdx.x >> 6));
    const int lane = threadIdx.x & 63;
    const int e0 = wv * EPW;

    float2 uu[EPW];
    float  rr[EPW];
    int    dd[EPW];
#pragma unroll
    for (int i = 0; i < EPW; ++i) {
        const int e = e0 + i;
        uu[i] = *(const float2*)(u + (size_t)e * 128 + lane * 2);
        rr[i] = rtab[(size_t)src[e] * 64 + lane];
        dd[i] = dst[e];
    }
#pragma unroll
    for (int i = 0; i < EPW; ++i) {
        const float a0 = GEPS - __logf(uu[i].x + GEPS);
        const float a1 = GEPS - __logf(uu[i].y + GEPS);
        const unsigned long long mone = __ballot(rr[i] * a0 > a1);
        if (lane == 0) {
            atomicOr(&masks[(size_t)dd[i] * 2 + 1], mone);
            atomicOr(&masks[(size_t)dd[i] * 2 + 0], ~mone);
        }
    }
}

// ======================= GEMM2: gates (M-tile 64, gate-regrouped, Bl dropped) =======================
// wave wid: row-half rh=wid&1 (rows wm=rh*32), col-half jh=wid>>1.
// acc[mf][g]: g=0 r, 1 z, 2 inn, 3 hn — all four gates for j = nb*32 + jh*16 + fr,
// so the GRU epilogue is wave-local. Weights-lo term (Ah*Bl) dropped: <=3e-3 preact err,
// does not affect gumbel decisions (rtab keeps full 3-pass).
__global__ __launch_bounds__(256) void gemm_gates(
    const __bf16* __restrict__ Aph, const __bf16* __restrict__ Apl,
    const __bf16* __restrict__ B2h,
    const float* __restrict__ bias2, const unsigned long long* __restrict__ masks,
    const float* __restrict__ W_comb, const float* __restrict__ h,
    float* __restrict__ out)
{
    const int bid = blockIdx.x;
    const int nb = bid & 3;
    const int m0 = (bid >> 2) * 64;

    const int t = threadIdx.x, lane = t & 63, wid = t >> 6;
    const int wm = (wid & 1) * 32;
    const int jh = wid >> 1;
    const int fr = lane & 15, fkh = lane >> 4;

    f32x4 acc[2][4];
#pragma unroll
    for (int i = 0; i < 2; ++i)
#pragma unroll
        for (int j = 0; j < 4; ++j) acc[i][j] = (f32x4){0.f, 0.f, 0.f, 0.f};

    for (int kt = 0; kt < 8; ++kt) {
        const size_t ab = (size_t)(kt * 4 + fkh) * NNP;
        const size_t bb = (size_t)(kt * 4 + fkh) * 512;
        bf16x8 ah[2], al[2];
#pragma unroll
        for (int mf = 0; mf < 2; ++mf) {
            const size_t ro = (ab + m0 + wm + mf * 16 + fr) * 8;
            ah[mf] = *(const bf16x8*)(Aph + ro);
            al[mf] = *(const bf16x8*)(Apl + ro);
        }
#pragma unroll
        for (int g = 0; g < 4; ++g) {
            const size_t ro = (bb + nb * 128 + g * 32 + jh * 16 + fr) * 8;
            const bf16x8 bh = *(const bf16x8*)(B2h + ro);
#pragma unroll
            for (int mf = 0; mf < 2; ++mf) {
                acc[mf][g] = __builtin_amdgcn_mfma_f32_16x16x32_bf16(ah[mf], bh, acc[mf][g], 0, 0, 0);
                acc[mf][g] = __builtin_amdgcn_mfma_f32_16x16x32_bf16(al[mf], bh, acc[mf][g], 0, 0, 0);
            }
        }
    }

    // ---- fused GRU epilogue (wave-local: all 4 gates present) ----
    float bia[4];
#pragma unroll
    for (int g = 0; g < 4; ++g) bia[g] = bias2[nb * 128 + g * 32 + jh * 16 + fr];
    const int j = nb * 32 + jh * 16 + fr;

#pragma unroll
    for (int mf = 0; mf < 2; ++mf)
#pragma unroll
        for (int rr = 0; rr < 4; ++rr) {
            const int gr = m0 + wm + mf * 16 + (lane >> 4) * 4 + rr;
            if (gr >= NN) continue;
            const unsigned long long ze = ~masks[(size_t)gr * 2 + 0];
            const unsigned long long zo = ~masks[(size_t)gr * 2 + 1];
            float rp = acc[mf][0][rr] + bia[0];
            float zp = acc[mf][1][rr] + bia[1];
            float ip = acc[mf][2][rr] + bia[2];
            float hp = acc[mf][3][rr] + bia[3];
            if (ze | zo) {
                unsigned long long bz = ze;
#pragma unroll 1
                while (bz) {
                    const int k = __builtin_ctzll(bz); bz &= bz - 1;
                    const int bit = 2 * k;
                    rp -= W_comb[(size_t)j * 128 + bit];
                    zp -= W_comb[(size_t)(128 + j) * 128 + bit];
                    ip -= W_comb[(size_t)(256 + j) * 128 + bit];
                }
                bz = zo;
#pragma unroll 1
                while (bz) {
                    const int k = __builtin_ctzll(bz); bz &= bz - 1;
                    const int bit = 2 * k + 1;
                    rp -= W_comb[(size_t)j * 128 + bit];
                    zp -= W_comb[(size_t)(128 + j) * 128 + bit];
                    ip -= W_comb[(size_t)(256 + j) * 128 + bit];
                }
            }
            const float hv = h[(size_t)gr * 128 + j];
            const float rg = fsigmoid(rp);
            const float zg = fsigmoid(zp);
            const float nv = ftanh(ip + rg * hp);
            const float o = (1.f - zg) * nv + zg * hv;
            out[(size_t)gr * 128 + j] = o;
            out[(size_t)(NN + gr) * 128 + j] = o;
        }
}

extern "C" void kernel_launch(void* const* d_in, const int* in_sizes, int n_in,
                              void* d_out, int out_size, void* d_ws, size_t ws_size,
                              hipStream_t stream) {
    const float* feat  = (const float*)d_in[0];
    const float* h     = (const float*)d_in[1];
    const int*   src   = (const int*)d_in[2];
    const int*   dst   = (const int*)d_in[3];
    const float* u     = (const float*)d_in[4];
    const float* W_enc = (const float*)d_in[5];
    const float* b_enc = (const float*)d_in[6];
    const float* W_dec = (const float*)d_in[7];
    const float* b_dec = (const float*)d_in[8];
    const float* W_ih  = (const float*)d_in[9];
    const float* W_hh  = (const float*)d_in[10];
    const float* b_ih  = (const float*)d_in[11];
    const float* b_hh  = (const float*)d_in[12];
    float* out = (float*)d_out;
    (void)in_sizes; (void)n_in; (void)out_size; (void)ws_size;

    char* ws = (char*)d_ws;
    float*              rtab   = (float*)(ws + 0);                    // 5,120,000 B
    unsigned long long* masks  = (unsigned long long*)(ws + 5120000); //   320,000 B
    __bf16*             B1h    = (__bf16*)(ws + 5440000);             //    65,536 B
    __bf16*             B1l    = (__bf16*)(ws + 5505536);             //    65,536 B
    __bf16*             B2h    = (__bf16*)(ws + 5571072);             //   262,144 B
    __bf16*             B2l    = (__bf16*)(ws + 5833216);             //   262,144 B
    float*              bias1  = (float*)(ws + 6095360);              //       512 B
    float*              bias2  = (float*)(ws + 6095872);              //     2,048 B
    float*              W_comb = (float*)(ws + 6097920);              //   196,608 B
    __bf16*             Aph    = (__bf16*)(ws + 6294528);             // 10,289,152 B
    __bf16*             Apl    = (__bf16*)(ws + 16583680);            // 10,289,152 B

    // pack weights + split A (fragment order) + fold biases + zero masks
    prep_k<<<914 + NNP / 8, 256, 0, stream>>>(
        feat, h, W_enc, b_enc, W_dec, b_dec, W_ih, W_hh, b_ih, b_hh,
        B1h, B1l, B2h, B2l, bias1, bias2, W_comb, (ulonglong2*)masks, Aph, Apl);

    // logits GEMM -> rtab (M=20000, N=128, K=256), 628 blocks
    gemm_rtab<<<NNP / 32, 256, 0, stream>>>(Aph, Apl, B1h, B1l, bias1, rtab);

    // per-edge gumbel argmax -> OR masks
    edge_k<<<NE / (4 * EPW), 256, 0, stream>>>(u, src, dst, rtab, masks);

    // gate GEMM + fused GRU epilogue -> out (M=20000, N=512, K=256), 1256 blocks
    gemm_gates<<<(NNP / 64) * 4, 256, 0, stream>>>(Aph, Apl, B2h, bias2, masks, W_comb, h, out);
}